// Round 1
// baseline (636.893 us; speedup 1.0000x reference)
//
#include <hip/hip_runtime.h>

#define TT 4096      // tokens (B*S)
#define HH 1024      // hidden
#define EE 8         // experts
#define II 2048      // intermediate
#define NP 8192      // pairs = 2*TT (top-2)
#define PPAD (NP + 128)

typedef unsigned short u16;
typedef __attribute__((ext_vector_type(8))) short bf16x8;
typedef __attribute__((ext_vector_type(4))) float f32x4;

__device__ __forceinline__ u16 f2b(float f) {
  union { float f; unsigned u; } v; v.f = f;
  unsigned u = v.u;
  u += 0x7fffu + ((u >> 16) & 1u);   // round-to-nearest-even
  return (u16)(u >> 16);
}
__device__ __forceinline__ float b2f(u16 b) {
  union { unsigned u; float f; } v; v.u = ((unsigned)b) << 16;
  return v.f;
}

typedef const __attribute__((address_space(1))) unsigned int ga_u32;
typedef __attribute__((address_space(3))) unsigned int lds_u32;
__device__ __forceinline__ void async16(const void* g, void* l) {
  __builtin_amdgcn_global_load_lds((ga_u32*)g, (lds_u32*)l, 16, 0, 0);
}

// ---------------- f32 -> bf16 conversion ----------------
__global__ void cvt_kernel(const float* __restrict__ src, u16* __restrict__ dst, int n) {
  int i = (blockIdx.x * blockDim.x + threadIdx.x) * 4;
  int stride = gridDim.x * blockDim.x * 4;
  for (; i < n; i += stride) {
    float4 v = *(const float4*)(src + i);
    ushort4 o;
    o.x = f2b(v.x); o.y = f2b(v.y); o.z = f2b(v.z); o.w = f2b(v.w);
    *(ushort4*)(dst + i) = o;
  }
}

// ---------------- router: logits, softmax, top-2 ----------------
__global__ void router_kernel(const float* __restrict__ xf, const float* __restrict__ rw,
                              int* __restrict__ sel, float* __restrict__ selw,
                              int* __restrict__ cnt) {
  const int wid = threadIdx.x >> 6;
  const int lane = threadIdx.x & 63;
  const int t = blockIdx.x * 4 + wid;
  if (t >= TT) return;
  float acc[EE];
  #pragma unroll
  for (int e = 0; e < EE; e++) acc[e] = 0.f;
  const float* xp = xf + (size_t)t * HH;
  for (int k = lane; k < HH; k += 64) {
    float xv = xp[k];
    #pragma unroll
    for (int e = 0; e < EE; e++) acc[e] += xv * rw[e * HH + k];
  }
  #pragma unroll
  for (int e = 0; e < EE; e++) {
    float v = acc[e];
    #pragma unroll
    for (int off = 32; off > 0; off >>= 1) v += __shfl_xor(v, off, 64);
    acc[e] = v;
  }
  if (lane == 0) {
    float m = acc[0];
    #pragma unroll
    for (int e = 1; e < EE; e++) m = fmaxf(m, acc[e]);
    float p[EE];
    #pragma unroll
    for (int e = 0; e < EE; e++) p[e] = __expf(acc[e] - m);
    int e1 = 0;
    #pragma unroll
    for (int e = 1; e < EE; e++) if (p[e] > p[e1]) e1 = e;
    int e2 = -1;
    #pragma unroll
    for (int e = 0; e < EE; e++) {
      if (e == e1) continue;
      if (e2 < 0 || p[e] > p[e2]) e2 = e;
    }
    float s = p[e1] + p[e2];
    sel[t * 2] = e1; sel[t * 2 + 1] = e2;
    selw[t * 2] = p[e1] / s; selw[t * 2 + 1] = p[e2] / s;
    atomicAdd(&cnt[e1], 1);
    atomicAdd(&cnt[e2], 1);
  }
}

__global__ void prefix_kernel(const int* __restrict__ cnt, int* __restrict__ base) {
  int s = 0;
  for (int e = 0; e < EE; e++) { base[e] = s; s += cnt[e]; }
}

__global__ void scatter_kernel(const int* __restrict__ sel, const float* __restrict__ selw,
                               const int* __restrict__ base, int* __restrict__ fill,
                               int* __restrict__ ptok, float* __restrict__ pwt) {
  int t = blockIdx.x * blockDim.x + threadIdx.x;
  if (t >= TT) return;
  #pragma unroll
  for (int k = 0; k < 2; k++) {
    int e = sel[t * 2 + k];
    int slot = atomicAdd(&fill[e], 1);
    int row = base[e] + slot;
    ptok[row] = t;
    pwt[row] = selw[t * 2 + k];
  }
}

// ---------------- GEMM1: h[row][0..4096) = x[tok] @ w1[e].T (gathered A) ----------------
__global__ __launch_bounds__(256, 2)
void gemm1_kernel(const u16* __restrict__ xb, const u16* __restrict__ w1b,
                  const int* __restrict__ ptok, const int* __restrict__ cnt,
                  const int* __restrict__ base, u16* __restrict__ hbuf) {
  const int e = blockIdx.z, mt = blockIdx.y, nt = blockIdx.x;
  const int mc = cnt[e];
  if (mt * 128 >= mc) return;
  const int mb = base[e];
  __shared__ u16 lA[128 * 32];
  __shared__ u16 lB[128 * 32];
  const int tid = threadIdx.x;
  const int lane = tid & 63;
  const int wid = tid >> 6;
  const int wm = wid >> 1, wn = wid & 1;
  const int r0 = tid >> 2, c0 = (tid & 3) * 8;
  int i0 = mb + mt * 128 + r0;
  int i1 = i0 + 64;
  i0 = min(i0, NP - 1); i1 = min(i1, NP - 1);
  const size_t t0 = (size_t)ptok[i0], t1 = (size_t)ptok[i1];
  const u16* a0 = xb + t0 * HH + c0;
  const u16* a1 = xb + t1 * HH + c0;
  const u16* b0 = w1b + (size_t)e * (2 * II) * HH + (size_t)(nt * 128 + r0) * HH + c0;
  const u16* b1 = b0 + (size_t)64 * HH;
  u16* la0 = &lA[r0 * 32 + c0];
  u16* la1 = &lA[(r0 + 64) * 32 + c0];
  u16* lb0 = &lB[r0 * 32 + c0];
  u16* lb1 = &lB[(r0 + 64) * 32 + c0];
  f32x4 acc[4][4];
  #pragma unroll
  for (int m = 0; m < 4; m++)
    #pragma unroll
    for (int n = 0; n < 4; n++) acc[m][n] = f32x4{0.f, 0.f, 0.f, 0.f};
  const int lr = lane & 15, lk = (lane >> 4) * 8;
  for (int kt = 0; kt < HH / 32; kt++) {
    async16(a0 + kt * 32, la0);
    async16(a1 + kt * 32, la1);
    async16(b0 + kt * 32, lb0);
    async16(b1 + kt * 32, lb1);
    __syncthreads();
    bf16x8 af[4], bfr[4];
    #pragma unroll
    for (int m = 0; m < 4; m++)
      af[m] = *(const bf16x8*)&lA[(wm * 64 + m * 16 + lr) * 32 + lk];
    #pragma unroll
    for (int n = 0; n < 4; n++)
      bfr[n] = *(const bf16x8*)&lB[(wn * 64 + n * 16 + lr) * 32 + lk];
    #pragma unroll
    for (int m = 0; m < 4; m++)
      #pragma unroll
      for (int n = 0; n < 4; n++)
        acc[m][n] = __builtin_amdgcn_mfma_f32_16x16x32_bf16(af[m], bfr[n], acc[m][n], 0, 0, 0);
    __syncthreads();
  }
  const int lrow = (lane >> 4) * 4;
  #pragma unroll
  for (int m = 0; m < 4; m++) {
    #pragma unroll
    for (int j = 0; j < 4; j++) {
      const int rl = wm * 64 + m * 16 + lrow + j;
      const int rg = mt * 128 + rl;
      if (rg < mc) {
        u16* hp = hbuf + (size_t)(mb + rg) * (2 * II) + nt * 128 + wn * 64 + lr;
        #pragma unroll
        for (int n = 0; n < 4; n++) hp[n * 16] = f2b(acc[m][n][j]);
      }
    }
  }
}

// ---------------- activation: act = silu(gate) * up ----------------
__global__ void act_kernel(const u16* __restrict__ hbuf, u16* __restrict__ actb) {
  size_t idx = (size_t)blockIdx.x * blockDim.x + threadIdx.x;
  size_t stride = (size_t)gridDim.x * blockDim.x;
  const size_t nq = (size_t)NP * (II / 4);
  for (size_t q = idx; q < nq; q += stride) {
    size_t r = q >> 9;            // / (II/4)
    size_t c = (q & 511) * 4;
    const u16* gp = hbuf + r * (2 * II) + c;
    ushort4 g = *(const ushort4*)gp;
    ushort4 u = *(const ushort4*)(gp + II);
    ushort4 o;
    float gv, uv;
    gv = b2f(g.x); uv = b2f(u.x); o.x = f2b(uv * gv / (1.f + __expf(-gv)));
    gv = b2f(g.y); uv = b2f(u.y); o.y = f2b(uv * gv / (1.f + __expf(-gv)));
    gv = b2f(g.z); uv = b2f(u.z); o.z = f2b(uv * gv / (1.f + __expf(-gv)));
    gv = b2f(g.w); uv = b2f(u.w); o.w = f2b(uv * gv / (1.f + __expf(-gv)));
    *(ushort4*)(actb + r * II + c) = o;
  }
}

// ---------------- GEMM2: out[tok] += wt * (act[row] @ w2[e].T) ----------------
__global__ __launch_bounds__(256, 2)
void gemm2_kernel(const u16* __restrict__ actb, const u16* __restrict__ w2b,
                  const int* __restrict__ ptok, const float* __restrict__ pwt,
                  const int* __restrict__ cnt, const int* __restrict__ base,
                  float* __restrict__ out) {
  const int e = blockIdx.z, mt = blockIdx.y, nt = blockIdx.x;
  const int mc = cnt[e];
  if (mt * 128 >= mc) return;
  const int mb = base[e];
  __shared__ u16 lA[128 * 32];
  __shared__ u16 lB[128 * 32];
  const int tid = threadIdx.x;
  const int lane = tid & 63;
  const int wid = tid >> 6;
  const int wm = wid >> 1, wn = wid & 1;
  const int r0 = tid >> 2, c0 = (tid & 3) * 8;
  const u16* a0 = actb + (size_t)(mb + mt * 128 + r0) * II + c0;
  const u16* a1 = a0 + (size_t)64 * II;
  const u16* b0 = w2b + (size_t)e * HH * II + (size_t)(nt * 128 + r0) * II + c0;
  const u16* b1 = b0 + (size_t)64 * II;
  u16* la0 = &lA[r0 * 32 + c0];
  u16* la1 = &lA[(r0 + 64) * 32 + c0];
  u16* lb0 = &lB[r0 * 32 + c0];
  u16* lb1 = &lB[(r0 + 64) * 32 + c0];
  f32x4 acc[4][4];
  #pragma unroll
  for (int m = 0; m < 4; m++)
    #pragma unroll
    for (int n = 0; n < 4; n++) acc[m][n] = f32x4{0.f, 0.f, 0.f, 0.f};
  const int lr = lane & 15, lk = (lane >> 4) * 8;
  for (int kt = 0; kt < II / 32; kt++) {
    async16(a0 + kt * 32, la0);
    async16(a1 + kt * 32, la1);
    async16(b0 + kt * 32, lb0);
    async16(b1 + kt * 32, lb1);
    __syncthreads();
    bf16x8 af[4], bfr[4];
    #pragma unroll
    for (int m = 0; m < 4; m++)
      af[m] = *(const bf16x8*)&lA[(wm * 64 + m * 16 + lr) * 32 + lk];
    #pragma unroll
    for (int n = 0; n < 4; n++)
      bfr[n] = *(const bf16x8*)&lB[(wn * 64 + n * 16 + lr) * 32 + lk];
    #pragma unroll
    for (int m = 0; m < 4; m++)
      #pragma unroll
      for (int n = 0; n < 4; n++)
        acc[m][n] = __builtin_amdgcn_mfma_f32_16x16x32_bf16(af[m], bfr[n], acc[m][n], 0, 0, 0);
    __syncthreads();
  }
  const int lrow = (lane >> 4) * 4;
  #pragma unroll
  for (int m = 0; m < 4; m++) {
    #pragma unroll
    for (int j = 0; j < 4; j++) {
      const int rl = wm * 64 + m * 16 + lrow + j;
      const int rg = mt * 128 + rl;
      if (rg < mc) {
        const int row = mb + rg;
        const int tok = ptok[row];
        const float wt = pwt[row];
        float* op = out + (size_t)tok * HH + nt * 128 + wn * 64 + lr;
        #pragma unroll
        for (int n = 0; n < 4; n++) atomicAdd(&op[n * 16], wt * acc[m][n][j]);
      }
    }
  }
}

extern "C" void kernel_launch(void* const* d_in, const int* in_sizes, int n_in,
                              void* d_out, int out_size, void* d_ws, size_t ws_size,
                              hipStream_t stream) {
  (void)in_sizes; (void)n_in; (void)out_size; (void)ws_size;
  const float* x  = (const float*)d_in[0];
  const float* rw = (const float*)d_in[1];
  const float* w1 = (const float*)d_in[2];
  const float* w2 = (const float*)d_in[3];
  float* out = (float*)d_out;
  char* ws = (char*)d_ws;
  size_t off = 0;
  u16* xb   = (u16*)(ws + off); off += (size_t)TT * HH * 2;            // 8 MB
  u16* w1b  = (u16*)(ws + off); off += (size_t)EE * 2 * II * HH * 2;   // 64 MB
  u16* w2b  = (u16*)(ws + off); off += (size_t)EE * HH * II * 2;       // 32 MB
  u16* hbuf = (u16*)(ws + off); off += (size_t)PPAD * 2 * II * 2;      // 65 MB
  u16* actb = (u16*)(ws + off); off += (size_t)PPAD * II * 2;          // 32.5 MB
  int*   ptok = (int*)(ws + off);   off += (size_t)NP * 4;
  float* pwt  = (float*)(ws + off); off += (size_t)NP * 4;
  int*   sel  = (int*)(ws + off);   off += (size_t)TT * 2 * 4;
  float* selw = (float*)(ws + off); off += (size_t)TT * 2 * 4;
  int* cnt   = (int*)(ws + off); off += 32;
  int* fill  = (int*)(ws + off); off += 32;
  int* basep = (int*)(ws + off); off += 32;

  hipMemsetAsync(cnt, 0, 96, stream);                        // cnt+fill+base
  hipMemsetAsync(out, 0, (size_t)TT * HH * 4, stream);

  cvt_kernel<<<2048, 256, 0, stream>>>(x,  xb,  TT * HH);
  cvt_kernel<<<4096, 256, 0, stream>>>(w1, w1b, EE * 2 * II * HH);
  cvt_kernel<<<4096, 256, 0, stream>>>(w2, w2b, EE * HH * II);

  router_kernel<<<TT / 4, 256, 0, stream>>>(x, rw, sel, selw, cnt);
  prefix_kernel<<<1, 1, 0, stream>>>(cnt, basep);
  scatter_kernel<<<TT / 256, 256, 0, stream>>>(sel, selw, basep, fill, ptok, pwt);

  gemm1_kernel<<<dim3(32, 64, 8), 256, 0, stream>>>(xb, w1b, ptok, cnt, basep, hbuf);
  act_kernel<<<2048, 256, 0, stream>>>(hbuf, actb);
  gemm2_kernel<<<dim3(8, 64, 8), 256, 0, stream>>>(actb, w2b, ptok, pwt, cnt, basep, out);
}

// Round 2
// 611.601 us; speedup vs baseline: 1.0414x; 1.0414x over previous
//
#include <hip/hip_runtime.h>

#define TT 4096      // tokens (B*S)
#define HH 1024      // hidden
#define EE 8         // experts
#define II 2048      // intermediate
#define NP 8192      // pairs = 2*TT (top-2)

typedef unsigned short u16;
typedef __attribute__((ext_vector_type(8))) short bf16x8;
typedef __attribute__((ext_vector_type(4))) float f32x4;

__device__ __forceinline__ u16 f2b(float f) {
  union { float f; unsigned u; } v; v.f = f;
  unsigned u = v.u;
  u += 0x7fffu + ((u >> 16) & 1u);   // round-to-nearest-even
  return (u16)(u >> 16);
}
__device__ __forceinline__ float b2f(u16 b) {
  union { unsigned u; float f; } v; v.u = ((unsigned)b) << 16;
  return v.f;
}

typedef const __attribute__((address_space(1))) unsigned int ga_u32;
typedef __attribute__((address_space(3))) unsigned int lds_u32;
__device__ __forceinline__ void async16(const void* g, void* l) {
  __builtin_amdgcn_global_load_lds((ga_u32*)g, (lds_u32*)l, 16, 0, 0);
}

// ---------------- f32 -> bf16 conversion ----------------
__global__ void cvt_kernel(const float* __restrict__ src, u16* __restrict__ dst, int n) {
  int i = (blockIdx.x * blockDim.x + threadIdx.x) * 4;
  int stride = gridDim.x * blockDim.x * 4;
  for (; i < n; i += stride) {
    float4 v = *(const float4*)(src + i);
    ushort4 o;
    o.x = f2b(v.x); o.y = f2b(v.y); o.z = f2b(v.z); o.w = f2b(v.w);
    *(ushort4*)(dst + i) = o;
  }
}

// ---------------- router: logits, softmax, top-2 ----------------
__global__ void router_kernel(const float* __restrict__ xf, const float* __restrict__ rw,
                              int* __restrict__ sel, float* __restrict__ selw,
                              int* __restrict__ cnt) {
  const int wid = threadIdx.x >> 6;
  const int lane = threadIdx.x & 63;
  const int t = blockIdx.x * 4 + wid;
  if (t >= TT) return;
  float acc[EE];
  #pragma unroll
  for (int e = 0; e < EE; e++) acc[e] = 0.f;
  const float* xp = xf + (size_t)t * HH;
  for (int k = lane; k < HH; k += 64) {
    float xv = xp[k];
    #pragma unroll
    for (int e = 0; e < EE; e++) acc[e] += xv * rw[e * HH + k];
  }
  #pragma unroll
  for (int e = 0; e < EE; e++) {
    float v = acc[e];
    #pragma unroll
    for (int off = 32; off > 0; off >>= 1) v += __shfl_xor(v, off, 64);
    acc[e] = v;
  }
  if (lane == 0) {
    float m = acc[0];
    #pragma unroll
    for (int e = 1; e < EE; e++) m = fmaxf(m, acc[e]);
    float p[EE];
    #pragma unroll
    for (int e = 0; e < EE; e++) p[e] = __expf(acc[e] - m);
    int e1 = 0;
    #pragma unroll
    for (int e = 1; e < EE; e++) if (p[e] > p[e1]) e1 = e;
    int e2 = -1;
    #pragma unroll
    for (int e = 0; e < EE; e++) {
      if (e == e1) continue;
      if (e2 < 0 || p[e] > p[e2]) e2 = e;
    }
    float s = p[e1] + p[e2];
    sel[t * 2] = e1; sel[t * 2 + 1] = e2;
    selw[t * 2] = p[e1] / s; selw[t * 2 + 1] = p[e2] / s;
    atomicAdd(&cnt[e1], 1);
    atomicAdd(&cnt[e2], 1);
  }
}

__global__ void prefix_kernel(const int* __restrict__ cnt, int* __restrict__ base) {
  int s = 0;
  for (int e = 0; e < EE; e++) { base[e] = s; s += cnt[e]; }
}

__global__ void scatter_kernel(const int* __restrict__ sel, const float* __restrict__ selw,
                               const int* __restrict__ base, int* __restrict__ fill,
                               int* __restrict__ ptok, float* __restrict__ pwt,
                               int* __restrict__ prow) {
  int t = blockIdx.x * blockDim.x + threadIdx.x;
  if (t >= TT) return;
  #pragma unroll
  for (int k = 0; k < 2; k++) {
    int e = sel[t * 2 + k];
    int slot = atomicAdd(&fill[e], 1);
    int row = base[e] + slot;
    ptok[row] = t;
    pwt[row] = selw[t * 2 + k];
    prow[t * 2 + k] = row;
  }
}

// ---- GEMM1 fused: act[row][nt*128..] = silu(x@w1_gate.T) * (x@w1_up.T) ----
__global__ __launch_bounds__(256, 2)
void gemm1_kernel(const u16* __restrict__ xb, const u16* __restrict__ w1b,
                  const int* __restrict__ ptok, const int* __restrict__ cnt,
                  const int* __restrict__ base, u16* __restrict__ actb) {
  const int e = blockIdx.z, mt = blockIdx.y, nt = blockIdx.x;  // nt in [0,16)
  const int mc = cnt[e];
  if (mt * 128 >= mc) return;
  const int mb = base[e];
  __shared__ u16 lA[128 * 32];
  __shared__ u16 lBg[128 * 32];
  __shared__ u16 lBu[128 * 32];
  const int tid = threadIdx.x;
  const int lane = tid & 63;
  const int wid = tid >> 6;
  const int wm = wid >> 1, wn = wid & 1;
  const int r0 = tid >> 2, c0 = (tid & 3) * 8;
  int i0 = mb + mt * 128 + r0;
  int i1 = i0 + 64;
  i0 = min(i0, NP - 1); i1 = min(i1, NP - 1);   // all NP entries of ptok are valid
  const size_t t0 = (size_t)ptok[i0], t1 = (size_t)ptok[i1];
  const u16* a0 = xb + t0 * HH + c0;
  const u16* a1 = xb + t1 * HH + c0;
  const u16* bg0 = w1b + (size_t)e * (2 * II) * HH + (size_t)(nt * 128 + r0) * HH + c0;
  const u16* bg1 = bg0 + (size_t)64 * HH;
  const u16* bu0 = bg0 + (size_t)II * HH;
  const u16* bu1 = bu0 + (size_t)64 * HH;
  u16* la0 = &lA[r0 * 32 + c0];
  u16* la1 = &lA[(r0 + 64) * 32 + c0];
  u16* lg0 = &lBg[r0 * 32 + c0];
  u16* lg1 = &lBg[(r0 + 64) * 32 + c0];
  u16* lu0 = &lBu[r0 * 32 + c0];
  u16* lu1 = &lBu[(r0 + 64) * 32 + c0];
  f32x4 accg[4][4], accu[4][4];
  #pragma unroll
  for (int m = 0; m < 4; m++)
    #pragma unroll
    for (int n = 0; n < 4; n++) {
      accg[m][n] = f32x4{0.f, 0.f, 0.f, 0.f};
      accu[m][n] = f32x4{0.f, 0.f, 0.f, 0.f};
    }
  const int lr = lane & 15, lk = (lane >> 4) * 8;
  for (int kt = 0; kt < HH / 32; kt++) {
    async16(a0 + kt * 32, la0);
    async16(a1 + kt * 32, la1);
    async16(bg0 + kt * 32, lg0);
    async16(bg1 + kt * 32, lg1);
    async16(bu0 + kt * 32, lu0);
    async16(bu1 + kt * 32, lu1);
    __syncthreads();
    bf16x8 af[4], gf[4], uf[4];
    #pragma unroll
    for (int m = 0; m < 4; m++)
      af[m] = *(const bf16x8*)&lA[(wm * 64 + m * 16 + lr) * 32 + lk];
    #pragma unroll
    for (int n = 0; n < 4; n++) {
      gf[n] = *(const bf16x8*)&lBg[(wn * 64 + n * 16 + lr) * 32 + lk];
      uf[n] = *(const bf16x8*)&lBu[(wn * 64 + n * 16 + lr) * 32 + lk];
    }
    #pragma unroll
    for (int m = 0; m < 4; m++)
      #pragma unroll
      for (int n = 0; n < 4; n++) {
        accg[m][n] = __builtin_amdgcn_mfma_f32_16x16x32_bf16(af[m], gf[n], accg[m][n], 0, 0, 0);
        accu[m][n] = __builtin_amdgcn_mfma_f32_16x16x32_bf16(af[m], uf[n], accu[m][n], 0, 0, 0);
      }
    __syncthreads();
  }
  const int lrow = (lane >> 4) * 4;
  #pragma unroll
  for (int m = 0; m < 4; m++) {
    #pragma unroll
    for (int j = 0; j < 4; j++) {
      const int rl = wm * 64 + m * 16 + lrow + j;
      const int rg = mt * 128 + rl;
      if (rg < mc) {
        u16* op = actb + (size_t)(mb + rg) * II + nt * 128 + wn * 64 + lr;
        #pragma unroll
        for (int n = 0; n < 4; n++) {
          float g = accg[m][n][j], u = accu[m][n][j];
          op[n * 16] = f2b(u * g / (1.f + __expf(-g)));
        }
      }
    }
  }
}

// ---------------- GEMM2: oe[row] = act[row] @ w2[e].T (bf16 out) ----------------
__global__ __launch_bounds__(256, 2)
void gemm2_kernel(const u16* __restrict__ actb, const u16* __restrict__ w2b,
                  const int* __restrict__ cnt, const int* __restrict__ base,
                  u16* __restrict__ oe) {
  const int e = blockIdx.z, mt = blockIdx.y, nt = blockIdx.x;
  const int mc = cnt[e];
  if (mt * 128 >= mc) return;
  const int mb = base[e];
  __shared__ u16 lA[128 * 32];
  __shared__ u16 lB[128 * 32];
  const int tid = threadIdx.x;
  const int lane = tid & 63;
  const int wid = tid >> 6;
  const int wm = wid >> 1, wn = wid & 1;
  const int r0 = tid >> 2, c0 = (tid & 3) * 8;
  const u16* a0 = actb + (size_t)(mb + mt * 128 + r0) * II + c0;
  const u16* a1 = a0 + (size_t)64 * II;
  const u16* b0 = w2b + (size_t)e * HH * II + (size_t)(nt * 128 + r0) * II + c0;
  const u16* b1 = b0 + (size_t)64 * II;
  u16* la0 = &lA[r0 * 32 + c0];
  u16* la1 = &lA[(r0 + 64) * 32 + c0];
  u16* lb0 = &lB[r0 * 32 + c0];
  u16* lb1 = &lB[(r0 + 64) * 32 + c0];
  f32x4 acc[4][4];
  #pragma unroll
  for (int m = 0; m < 4; m++)
    #pragma unroll
    for (int n = 0; n < 4; n++) acc[m][n] = f32x4{0.f, 0.f, 0.f, 0.f};
  const int lr = lane & 15, lk = (lane >> 4) * 8;
  for (int kt = 0; kt < II / 32; kt++) {
    async16(a0 + kt * 32, la0);
    async16(a1 + kt * 32, la1);
    async16(b0 + kt * 32, lb0);
    async16(b1 + kt * 32, lb1);
    __syncthreads();
    bf16x8 af[4], bfr[4];
    #pragma unroll
    for (int m = 0; m < 4; m++)
      af[m] = *(const bf16x8*)&lA[(wm * 64 + m * 16 + lr) * 32 + lk];
    #pragma unroll
    for (int n = 0; n < 4; n++)
      bfr[n] = *(const bf16x8*)&lB[(wn * 64 + n * 16 + lr) * 32 + lk];
    #pragma unroll
    for (int m = 0; m < 4; m++)
      #pragma unroll
      for (int n = 0; n < 4; n++)
        acc[m][n] = __builtin_amdgcn_mfma_f32_16x16x32_bf16(af[m], bfr[n], acc[m][n], 0, 0, 0);
    __syncthreads();
  }
  const int lrow = (lane >> 4) * 4;
  #pragma unroll
  for (int m = 0; m < 4; m++) {
    #pragma unroll
    for (int j = 0; j < 4; j++) {
      const int rl = wm * 64 + m * 16 + lrow + j;
      const int rg = mt * 128 + rl;
      if (rg < mc) {
        u16* op = oe + (size_t)(mb + rg) * HH + nt * 128 + wn * 64 + lr;
        #pragma unroll
        for (int n = 0; n < 4; n++) op[n * 16] = f2b(acc[m][n][j]);
      }
    }
  }
}

// ---------------- combine: out[t] = wa*oe[rowa] + wb*oe[rowb] ----------------
__global__ void combine_kernel(const u16* __restrict__ oe, const int* __restrict__ prow,
                               const float* __restrict__ pwt, float* __restrict__ out) {
  int idx = blockIdx.x * blockDim.x + threadIdx.x;   // one per 8-col chunk
  const int chunks = HH / 8;
  if (idx >= TT * chunks) return;
  int t = idx / chunks;
  int c = (idx % chunks) * 8;
  int ra = prow[t * 2], rb = prow[t * 2 + 1];
  float wa = pwt[ra], wb = pwt[rb];
  const ushort4* pa = (const ushort4*)(oe + (size_t)ra * HH + c);
  const ushort4* pb = (const ushort4*)(oe + (size_t)rb * HH + c);
  float4* po = (float4*)(out + (size_t)t * HH + c);
  #pragma unroll
  for (int h = 0; h < 2; h++) {
    ushort4 va = pa[h], vb = pb[h];
    float4 o;
    o.x = wa * b2f(va.x) + wb * b2f(vb.x);
    o.y = wa * b2f(va.y) + wb * b2f(vb.y);
    o.z = wa * b2f(va.z) + wb * b2f(vb.z);
    o.w = wa * b2f(va.w) + wb * b2f(vb.w);
    po[h] = o;
  }
}

extern "C" void kernel_launch(void* const* d_in, const int* in_sizes, int n_in,
                              void* d_out, int out_size, void* d_ws, size_t ws_size,
                              hipStream_t stream) {
  (void)in_sizes; (void)n_in; (void)out_size; (void)ws_size;
  const float* x  = (const float*)d_in[0];
  const float* rw = (const float*)d_in[1];
  const float* w1 = (const float*)d_in[2];
  const float* w2 = (const float*)d_in[3];
  float* out = (float*)d_out;
  char* ws = (char*)d_ws;
  size_t off = 0;
  u16* xb   = (u16*)(ws + off); off += (size_t)TT * HH * 2;            // 8.4 MB
  u16* w1b  = (u16*)(ws + off); off += (size_t)EE * 2 * II * HH * 2;   // 67 MB
  u16* w2b  = (u16*)(ws + off); off += (size_t)EE * HH * II * 2;       // 33.5 MB
  u16* actb = (u16*)(ws + off); off += (size_t)NP * II * 2;            // 33.5 MB
  u16* oe   = (u16*)(ws + off); off += (size_t)NP * HH * 2;            // 16.8 MB
  int*   ptok = (int*)(ws + off);   off += (size_t)NP * 4;
  float* pwt  = (float*)(ws + off); off += (size_t)NP * 4;
  int*   prow = (int*)(ws + off);   off += (size_t)NP * 4;
  int*   sel  = (int*)(ws + off);   off += (size_t)TT * 2 * 4;
  float* selw = (float*)(ws + off); off += (size_t)TT * 2 * 4;
  int* cnt   = (int*)(ws + off); off += 32;
  int* fill  = (int*)(ws + off); off += 32;
  int* basep = (int*)(ws + off); off += 32;

  hipMemsetAsync(cnt, 0, 96, stream);                        // cnt+fill+base

  cvt_kernel<<<2048, 256, 0, stream>>>(x,  xb,  TT * HH);
  cvt_kernel<<<4096, 256, 0, stream>>>(w1, w1b, EE * 2 * II * HH);
  cvt_kernel<<<4096, 256, 0, stream>>>(w2, w2b, EE * HH * II);

  router_kernel<<<TT / 4, 256, 0, stream>>>(x, rw, sel, selw, cnt);
  prefix_kernel<<<1, 1, 0, stream>>>(cnt, basep);
  scatter_kernel<<<TT / 256, 256, 0, stream>>>(sel, selw, basep, fill, ptok, pwt, prow);

  gemm1_kernel<<<dim3(16, 64, 8), 256, 0, stream>>>(xb, w1b, ptok, cnt, basep, actb);
  gemm2_kernel<<<dim3(8, 64, 8), 256, 0, stream>>>(actb, w2b, cnt, basep, oe);
  combine_kernel<<<(TT * (HH / 8) + 255) / 256, 256, 0, stream>>>(oe, prow, pwt, out);
}

// Round 5
// 489.955 us; speedup vs baseline: 1.2999x; 1.2483x over previous
//
#include <hip/hip_runtime.h>

#define TT 4096      // tokens (B*S)
#define HH 1024      // hidden
#define EE 8         // experts
#define II 2048      // intermediate
#define NP 8192      // pairs = 2*TT (top-2)
#define MAXTILES 72  // sum_e ceil(cnt_e/128) <= 64 + 7, padded

typedef unsigned short u16;
typedef __attribute__((ext_vector_type(8))) short bf16x8;
typedef __attribute__((ext_vector_type(4))) float f32x4;

__device__ __forceinline__ u16 f2b(float f) {
  union { float f; unsigned u; } v; v.f = f;
  unsigned u = v.u;
  u += 0x7fffu + ((u >> 16) & 1u);   // round-to-nearest-even
  return (u16)(u >> 16);
}
__device__ __forceinline__ float b2f(u16 b) {
  union { unsigned u; float f; } v; v.u = ((unsigned)b) << 16;
  return v.f;
}

typedef const __attribute__((address_space(1))) unsigned int ga_u32;
typedef __attribute__((address_space(3))) unsigned int lds_u32;
__device__ __forceinline__ void async16(const void* g, void* l) {
  __builtin_amdgcn_global_load_lds((ga_u32*)g, (lds_u32*)l, 16, 0, 0);
}

// ---------------- f32 -> bf16 conversion ----------------
__global__ void cvt_kernel(const float* __restrict__ src, u16* __restrict__ dst, int n) {
  int i = (blockIdx.x * blockDim.x + threadIdx.x) * 4;
  int stride = gridDim.x * blockDim.x * 4;
  for (; i < n; i += stride) {
    float4 v = *(const float4*)(src + i);
    ushort4 o;
    o.x = f2b(v.x); o.y = f2b(v.y); o.z = f2b(v.z); o.w = f2b(v.w);
    *(ushort4*)(dst + i) = o;
  }
}

// ---------------- router: logits, softmax, top-2 (no atomics) ----------------
__global__ void router_kernel(const float* __restrict__ xf, const float* __restrict__ rw,
                              int* __restrict__ sel, float* __restrict__ selw) {
  const int wid = threadIdx.x >> 6;
  const int lane = threadIdx.x & 63;
  const int t = blockIdx.x * 4 + wid;
  if (t >= TT) return;
  float acc[EE];
  #pragma unroll
  for (int e = 0; e < EE; e++) acc[e] = 0.f;
  const float* xp = xf + (size_t)t * HH;
  for (int k = lane; k < HH; k += 64) {
    float xv = xp[k];
    #pragma unroll
    for (int e = 0; e < EE; e++) acc[e] += xv * rw[e * HH + k];
  }
  #pragma unroll
  for (int e = 0; e < EE; e++) {
    float v = acc[e];
    #pragma unroll
    for (int off = 32; off > 0; off >>= 1) v += __shfl_xor(v, off, 64);
    acc[e] = v;
  }
  if (lane == 0) {
    float m = acc[0];
    #pragma unroll
    for (int e = 1; e < EE; e++) m = fmaxf(m, acc[e]);
    float p[EE];
    #pragma unroll
    for (int e = 0; e < EE; e++) p[e] = __expf(acc[e] - m);
    int e1 = 0;
    #pragma unroll
    for (int e = 1; e < EE; e++) if (p[e] > p[e1]) e1 = e;
    int e2 = -1;
    #pragma unroll
    for (int e = 0; e < EE; e++) {
      if (e == e1) continue;
      if (e2 < 0 || p[e] > p[e2]) e2 = e;
    }
    float s = p[e1] + p[e2];
    sel[t * 2] = e1; sel[t * 2 + 1] = e2;
    selw[t * 2] = p[e1] / s; selw[t * 2 + 1] = p[e2] / s;
  }
}

// ---------------- count: wave-aggregated (uniform-address atomics) ----------------
__global__ void count_kernel(const int* __restrict__ sel, int* __restrict__ cnt) {
  int idx = blockIdx.x * blockDim.x + threadIdx.x;
  int e = (idx < NP) ? sel[idx] : -1;
  #pragma unroll
  for (int ee = 0; ee < EE; ee++) {
    if (e == ee) atomicAdd(&cnt[ee], 1);   // uniform addr -> compiler wave-aggregates
  }
}

// ---------------- prefix + tile table ----------------
__global__ void prefix_kernel(const int* __restrict__ cnt, int* __restrict__ base,
                              int* __restrict__ tile_e, int* __restrict__ tile_m,
                              int* __restrict__ n_tiles) {
  int s = 0, nt = 0;
  for (int e = 0; e < EE; e++) {
    base[e] = s;
    int c = cnt[e];
    for (int m = 0; m * 128 < c; m++) { tile_e[nt] = e; tile_m[nt] = m; nt++; }
    s += c;
  }
  *n_tiles = nt;
}

// ---------------- scatter: wave-aggregated slot assignment ----------------
__global__ void scatter_kernel(const int* __restrict__ sel, const float* __restrict__ selw,
                               const int* __restrict__ base, int* __restrict__ fill,
                               int* __restrict__ ptok, float* __restrict__ pwt,
                               int* __restrict__ prow) {
  int idx = blockIdx.x * blockDim.x + threadIdx.x;   // pair slot
  if (idx >= NP) return;
  int t = idx >> 1;
  int e = sel[idx];
  #pragma unroll
  for (int ee = 0; ee < EE; ee++) {
    if (e == ee) {
      int slot = atomicAdd(&fill[ee], 1);            // uniform addr -> wave-aggregated
      int row = base[ee] + slot;
      ptok[row] = t;
      pwt[row] = selw[idx];
      prow[idx] = row;
    }
  }
}

// ---- GEMM1 fused (2-phase dbuf): act[row] = silu(x@w1g.T) * (x@w1u.T) ----
#define G1SEG 4096          // u16 elems per 128x32 panel
__global__ __launch_bounds__(256, 2)
void gemm1_kernel(const u16* __restrict__ xb, const u16* __restrict__ w1b,
                  const int* __restrict__ ptok, const int* __restrict__ cnt,
                  const int* __restrict__ base,
                  const int* __restrict__ tile_e, const int* __restrict__ tile_m,
                  const int* __restrict__ n_tiles, u16* __restrict__ actb) {
  const int ti = blockIdx.y;
  if (ti >= *n_tiles) return;
  const int e = tile_e[ti], mt = tile_m[ti], nt = blockIdx.x;
  const int mc = cnt[e], mb = base[e];
  __shared__ u16 L[2][3 * G1SEG];
  const int tid = threadIdx.x;
  const int lane = tid & 63;
  const int wid = tid >> 6;
  const int wm = wid >> 1, wn = wid & 1;
  const int r0 = tid >> 2, c0 = (tid & 3) * 8;
  int i0 = mb + mt * 128 + r0;
  int i1 = i0 + 64;
  i0 = min(i0, NP - 1); i1 = min(i1, NP - 1);
  const size_t t0 = (size_t)ptok[i0], t1 = (size_t)ptok[i1];
  const u16* a0 = xb + t0 * HH + c0;
  const u16* a1 = xb + t1 * HH + c0;
  const u16* bg0 = w1b + (size_t)e * (2 * II) * HH + (size_t)(nt * 128 + r0) * HH + c0;
  const u16* bg1 = bg0 + (size_t)64 * HH;
  const u16* bu0 = bg0 + (size_t)II * HH;
  const u16* bu1 = bu0 + (size_t)64 * HH;
  const int o0 = r0 * 32 + c0;
  const int o1 = (r0 + 64) * 32 + c0;
  f32x4 accg[4][4], accu[4][4];
  #pragma unroll
  for (int m = 0; m < 4; m++)
    #pragma unroll
    for (int n = 0; n < 4; n++) {
      accg[m][n] = f32x4{0.f, 0.f, 0.f, 0.f};
      accu[m][n] = f32x4{0.f, 0.f, 0.f, 0.f};
    }
  const int lr = lane & 15, lk = (lane >> 4) * 8;

  #define G1STAGE(b, kt) { u16* Lb = &L[b][0];                 \
    async16(a0  + (kt) * 32, Lb + o0);                          \
    async16(a1  + (kt) * 32, Lb + o1);                          \
    async16(bg0 + (kt) * 32, Lb + G1SEG + o0);                  \
    async16(bg1 + (kt) * 32, Lb + G1SEG + o1);                  \
    async16(bu0 + (kt) * 32, Lb + 2 * G1SEG + o0);              \
    async16(bu1 + (kt) * 32, Lb + 2 * G1SEG + o1); }

  G1STAGE(0, 0);
  __syncthreads();
  int cur = 0;
  const int NT = HH / 32;
  for (int kt = 0; kt < NT; ++kt) {
    if (kt + 1 < NT) G1STAGE(cur ^ 1, kt + 1);
    const u16* Lb = &L[cur][0];
    bf16x8 af[4], gf[4], uf[4];
    #pragma unroll
    for (int m = 0; m < 4; m++)
      af[m] = *(const bf16x8*)(Lb + (wm * 64 + m * 16 + lr) * 32 + lk);
    #pragma unroll
    for (int n = 0; n < 4; n++) {
      gf[n] = *(const bf16x8*)(Lb + G1SEG + (wn * 64 + n * 16 + lr) * 32 + lk);
      uf[n] = *(const bf16x8*)(Lb + 2 * G1SEG + (wn * 64 + n * 16 + lr) * 32 + lk);
    }
    #pragma unroll
    for (int m = 0; m < 4; m++)
      #pragma unroll
      for (int n = 0; n < 4; n++) {
        accg[m][n] = __builtin_amdgcn_mfma_f32_16x16x32_bf16(af[m], gf[n], accg[m][n], 0, 0, 0);
        accu[m][n] = __builtin_amdgcn_mfma_f32_16x16x32_bf16(af[m], uf[n], accu[m][n], 0, 0, 0);
      }
    __syncthreads();      // drains next-tile loads (vmcnt0) + guards buffer reuse
    cur ^= 1;
  }
  const int lrow = (lane >> 4) * 4;
  #pragma unroll
  for (int m = 0; m < 4; m++) {
    #pragma unroll
    for (int j = 0; j < 4; j++) {
      const int rl = wm * 64 + m * 16 + lrow + j;
      const int rg = mt * 128 + rl;
      if (rg < mc) {
        u16* op = actb + (size_t)(mb + rg) * II + nt * 128 + wn * 64 + lr;
        #pragma unroll
        for (int n = 0; n < 4; n++) {
          float g = accg[m][n][j], u = accu[m][n][j];
          op[n * 16] = f2b(u * g / (1.f + __expf(-g)));
        }
      }
    }
  }
}

// ---------------- GEMM2 (2-phase dbuf): oe[row] = act[row] @ w2[e].T ----------------
#define G2SEG 4096
__global__ __launch_bounds__(256, 2)
void gemm2_kernel(const u16* __restrict__ actb, const u16* __restrict__ w2b,
                  const int* __restrict__ cnt, const int* __restrict__ base,
                  const int* __restrict__ tile_e, const int* __restrict__ tile_m,
                  const int* __restrict__ n_tiles, u16* __restrict__ oe) {
  const int ti = blockIdx.y;
  if (ti >= *n_tiles) return;
  const int e = tile_e[ti], mt = tile_m[ti], nt = blockIdx.x;
  const int mc = cnt[e], mb = base[e];
  __shared__ u16 L[2][2 * G2SEG];
  const int tid = threadIdx.x;
  const int lane = tid & 63;
  const int wid = tid >> 6;
  const int wm = wid >> 1, wn = wid & 1;
  const int r0 = tid >> 2, c0 = (tid & 3) * 8;
  const u16* a0 = actb + (size_t)(mb + mt * 128 + r0) * II + c0;
  const u16* a1 = a0 + (size_t)64 * II;
  const u16* b0 = w2b + (size_t)e * HH * II + (size_t)(nt * 128 + r0) * II + c0;
  const u16* b1 = b0 + (size_t)64 * II;
  const int o0 = r0 * 32 + c0;
  const int o1 = (r0 + 64) * 32 + c0;
  f32x4 acc[4][4];
  #pragma unroll
  for (int m = 0; m < 4; m++)
    #pragma unroll
    for (int n = 0; n < 4; n++) acc[m][n] = f32x4{0.f, 0.f, 0.f, 0.f};
  const int lr = lane & 15, lk = (lane >> 4) * 8;

  #define G2STAGE(b, kt) { u16* Lb = &L[b][0];                 \
    async16(a0 + (kt) * 32, Lb + o0);                           \
    async16(a1 + (kt) * 32, Lb + o1);                           \
    async16(b0 + (kt) * 32, Lb + G2SEG + o0);                   \
    async16(b1 + (kt) * 32, Lb + G2SEG + o1); }

  G2STAGE(0, 0);
  __syncthreads();
  int cur = 0;
  const int NT = II / 32;
  for (int kt = 0; kt < NT; ++kt) {
    if (kt + 1 < NT) G2STAGE(cur ^ 1, kt + 1);
    const u16* Lb = &L[cur][0];
    bf16x8 af[4], bfr[4];
    #pragma unroll
    for (int m = 0; m < 4; m++)
      af[m] = *(const bf16x8*)(Lb + (wm * 64 + m * 16 + lr) * 32 + lk);
    #pragma unroll
    for (int n = 0; n < 4; n++)
      bfr[n] = *(const bf16x8*)(Lb + G2SEG + (wn * 64 + n * 16 + lr) * 32 + lk);
    #pragma unroll
    for (int m = 0; m < 4; m++)
      #pragma unroll
      for (int n = 0; n < 4; n++)
        acc[m][n] = __builtin_amdgcn_mfma_f32_16x16x32_bf16(af[m], bfr[n], acc[m][n], 0, 0, 0);
    __syncthreads();
    cur ^= 1;
  }
  const int lrow = (lane >> 4) * 4;
  #pragma unroll
  for (int m = 0; m < 4; m++) {
    #pragma unroll
    for (int j = 0; j < 4; j++) {
      const int rl = wm * 64 + m * 16 + lrow + j;
      const int rg = mt * 128 + rl;
      if (rg < mc) {
        u16* op = oe + (size_t)(mb + rg) * HH + nt * 128 + wn * 64 + lr;
        #pragma unroll
        for (int n = 0; n < 4; n++) op[n * 16] = f2b(acc[m][n][j]);
      }
    }
  }
}

// ---------------- combine: out[t] = wa*oe[rowa] + wb*oe[rowb] ----------------
__global__ void combine_kernel(const u16* __restrict__ oe, const int* __restrict__ prow,
                               const float* __restrict__ pwt, float* __restrict__ out) {
  int idx = blockIdx.x * blockDim.x + threadIdx.x;   // one per 8-col chunk
  const int chunks = HH / 8;
  if (idx >= TT * chunks) return;
  int t = idx / chunks;
  int c = (idx % chunks) * 8;
  int ra = prow[t * 2], rb = prow[t * 2 + 1];
  float wa = pwt[ra], wb = pwt[rb];
  const ushort4* pa = (const ushort4*)(oe + (size_t)ra * HH + c);
  const ushort4* pb = (const ushort4*)(oe + (size_t)rb * HH + c);
  float4* po = (float4*)(out + (size_t)t * HH + c);
  #pragma unroll
  for (int h = 0; h < 2; h++) {
    ushort4 va = pa[h], vb = pb[h];
    float4 o;
    o.x = wa * b2f(va.x) + wb * b2f(vb.x);
    o.y = wa * b2f(va.y) + wb * b2f(vb.y);
    o.z = wa * b2f(va.z) + wb * b2f(vb.z);
    o.w = wa * b2f(va.w) + wb * b2f(vb.w);
    po[h] = o;
  }
}

extern "C" void kernel_launch(void* const* d_in, const int* in_sizes, int n_in,
                              void* d_out, int out_size, void* d_ws, size_t ws_size,
                              hipStream_t stream) {
  (void)in_sizes; (void)n_in; (void)out_size; (void)ws_size;
  const float* x  = (const float*)d_in[0];
  const float* rw = (const float*)d_in[1];
  const float* w1 = (const float*)d_in[2];
  const float* w2 = (const float*)d_in[3];
  float* out = (float*)d_out;
  char* ws = (char*)d_ws;
  size_t off = 0;
  u16* xb   = (u16*)(ws + off); off += (size_t)TT * HH * 2;            // 8.4 MB
  u16* w1b  = (u16*)(ws + off); off += (size_t)EE * 2 * II * HH * 2;   // 67 MB
  u16* w2b  = (u16*)(ws + off); off += (size_t)EE * HH * II * 2;       // 33.5 MB
  u16* actb = (u16*)(ws + off); off += (size_t)(NP + 128) * II * 2;    // 34 MB (pad for tile overreach)
  u16* oe   = (u16*)(ws + off); off += (size_t)NP * HH * 2;            // 16.8 MB
  int*   ptok = (int*)(ws + off);   off += (size_t)NP * 4;
  float* pwt  = (float*)(ws + off); off += (size_t)NP * 4;
  int*   prow = (int*)(ws + off);   off += (size_t)NP * 4;
  int*   sel  = (int*)(ws + off);   off += (size_t)TT * 2 * 4;
  float* selw = (float*)(ws + off); off += (size_t)TT * 2 * 4;
  int* cnt    = (int*)(ws + off); off += 32 * 4;
  int* fill   = (int*)(ws + off); off += 32 * 4;
  int* basep  = (int*)(ws + off); off += 32 * 4;
  int* tile_e = (int*)(ws + off); off += MAXTILES * 4;
  int* tile_m = (int*)(ws + off); off += MAXTILES * 4;
  int* ntile  = (int*)(ws + off); off += 16;

  hipMemsetAsync(cnt, 0, 64 * 4, stream);   // cnt + fill

  cvt_kernel<<<2048, 256, 0, stream>>>(x,  xb,  TT * HH);
  cvt_kernel<<<4096, 256, 0, stream>>>(w1, w1b, EE * 2 * II * HH);
  cvt_kernel<<<4096, 256, 0, stream>>>(w2, w2b, EE * HH * II);

  router_kernel<<<TT / 4, 256, 0, stream>>>(x, rw, sel, selw);
  count_kernel<<<NP / 256, 256, 0, stream>>>(sel, cnt);
  prefix_kernel<<<1, 1, 0, stream>>>(cnt, basep, tile_e, tile_m, ntile);
  scatter_kernel<<<NP / 256, 256, 0, stream>>>(sel, selw, basep, fill, ptok, pwt, prow);

  gemm1_kernel<<<dim3(16, MAXTILES), 256, 0, stream>>>(xb, w1b, ptok, cnt, basep,
                                                       tile_e, tile_m, ntile, actb);
  gemm2_kernel<<<dim3(8, MAXTILES), 256, 0, stream>>>(actb, w2b, cnt, basep,
                                                      tile_e, tile_m, ntile, oe);
  combine_kernel<<<(TT * (HH / 8) + 255) / 256, 256, 0, stream>>>(oe, prow, pwt, out);
}